// Round 9
// baseline (175.797 us; speedup 1.0000x reference)
//
#include <hip/hip_runtime.h>
#include <hip/hip_bf16.h>

#define K_DIM 8192
#define L_DIM 1024
#define C2 240
#define MSTRIDE 256                 // padded m stride in partials
#define BM 128
#define BN 128
#define BK 64
#define KSPLIT 16
#define KCHUNK 512                  // K_DIM / KSPLIT
#define NSTEP 8                     // KCHUNK / BK
#define PART_KC (L_DIM * MSTRIDE)   // 262144 bf16 elems per k-chunk
#define PART_BYTES ((size_t)KSPLIT * PART_KC * 2)  // 8,388,608
#define NTILES 8                    // L_DIM / BN
#define CONTRIB (2 * KSPLIT)        // mtiles * kc contributors per n-tile
#define TOT_F4 (10000 * 256)

typedef __attribute__((ext_vector_type(4))) float f32x4;
typedef __attribute__((ext_vector_type(2))) float f32x2;
typedef __attribute__((ext_vector_type(8))) short bf16x8;
typedef __attribute__((ext_vector_type(4))) short bf16x4;

__device__ __forceinline__ unsigned short f2bf(float f) {
  return __builtin_bit_cast(unsigned short, __float2bfloat16(f));
}
__device__ __forceinline__ float bf2f(unsigned short h) {
  unsigned u = ((unsigned)h) << 16;
  return __builtin_bit_cast(float, u);
}

// ---------------- Stage 1: GEMM + split-K last-block reduction -------------
// part[kc][n][m(pad 256)] = (W[240][8192] @ A[8192][1024]) k-chunk partials.
// 256 blocks x 512 thr (8 waves: 2m x 4n of 64x32). R8's proven GEMM body.
// NEW: per n-tile counter; the 32nd (last) contributor — no spin, it sees
// old==CONTRIB-1 at its own atomicAdd — reduces its tile's partials (1MB,
// L2-hot) into colbuf[128 cols]. CUTLASS split-K pattern; deterministic
// (fixed reduction order; reducer identity doesn't change values).
__global__ __launch_bounds__(512, 2) void k_gemm_red(
    const float* __restrict__ Wm, const float* __restrict__ Am,
    const float* __restrict__ b3, const float* __restrict__ w4,
    const float* __restrict__ b4, unsigned short* __restrict__ part,
    float* __restrict__ colbuf, int* __restrict__ ctrs)
{
  __shared__ __align__(16) unsigned short sW[2 * BM * BK];  // 32 KB dbuf
  __shared__ __align__(16) unsigned short sA[2 * BN * BK];  // 32 KB dbuf
  __shared__ float red[2][2][4];
  __shared__ int s_old;

  const int t    = threadIdx.x;
  const int lane = t & 63;
  const int bid  = blockIdx.x;

  // XCD-chunked remap (bijective, 256 % 8 == 0): XCD owns 2 kc x all tiles.
  const int wk    = (bid & 7) * 32 + (bid >> 3);
  const int nt8   = wk & 7;
  const int mtile = (wk >> 3) & 1;
  const int kc    = wk >> 4;            // 0..15

  const int wid = t >> 6;
  const int mg  = wid >> 2;       // 2 groups of 64 m
  const int ng  = wid & 3;        // 4 groups of 32 n
  const int l15 = lane & 15;
  const int lk8 = (lane >> 4) * 8;

  const int n0b = nt8 * BN;
  const int m0b = mtile * BM;
  const int k0  = kc * KCHUNK;

  // W staging: thread -> (row t>>2, 16 k at (t&3)*16); 4 f32x4 loads.
  const int swm = t >> 2;
  const int swk = (t & 3) * 16;
  // A staging: thread -> (2 cols at 2*(t&63), 8 k at wid*8); 8 f32x2 loads.
  const int san = (t & 63) * 2;
  const int sak = (t >> 6) * 8;

  const float* wp = Wm + (size_t)(m0b + swm) * K_DIM + k0 + swk;
  const float* ap = Am + (size_t)(k0 + sak) * L_DIM + n0b + san;
  const bool wok = (m0b + swm) < C2;

  f32x4 wregs[2][4];
  f32x2 aregs[2][8];
  f32x4 acc[4][2];
#pragma unroll
  for (int i = 0; i < 4; ++i)
#pragma unroll
    for (int j = 0; j < 2; ++j) acc[i][j] = (f32x4){0.f, 0.f, 0.f, 0.f};

  // prologue: issue loads for steps 0 and 1 (depth-2)
#pragma unroll
  for (int p = 0; p < 2; ++p) {
#pragma unroll
    for (int j = 0; j < 4; ++j)
      wregs[p][j] = wok ? *(const f32x4*)(wp + p * BK + 4 * j)
                        : (f32x4){0.f, 0.f, 0.f, 0.f};
#pragma unroll
    for (int r = 0; r < 8; ++r)
      aregs[p][r] = *(const f32x2*)(ap + (size_t)(p * BK + r) * L_DIM);
  }

#pragma unroll
  for (int s = 0; s < NSTEP; ++s) {
    unsigned short* swb = sW + (s & 1) * (BM * BK);
    unsigned short* sab = sA + (s & 1) * (BN * BK);

    // ---- convert + swizzled LDS write from reg set s&1 ----
#pragma unroll
    for (int j = 0; j < 2; ++j) {       // two bf16x8 per thread (16 k)
      f32x4 a = wregs[s & 1][2 * j], b = wregs[s & 1][2 * j + 1];
      bf16x8 v;
      v[0] = (short)f2bf(a[0]); v[1] = (short)f2bf(a[1]);
      v[2] = (short)f2bf(a[2]); v[3] = (short)f2bf(a[3]);
      v[4] = (short)f2bf(b[0]); v[5] = (short)f2bf(b[1]);
      v[6] = (short)f2bf(b[2]); v[7] = (short)f2bf(b[3]);
      *(bf16x8*)&swb[swm * BK + ((swk + 8 * j) ^ ((swm & 7) << 3))] = v;
    }
#pragma unroll
    for (int j = 0; j < 2; ++j) {       // two cols, 8 k each
      const int n = san + j;
      bf16x8 v;
#pragma unroll
      for (int r = 0; r < 8; ++r)
        v[r] = (short)f2bf(j ? aregs[s & 1][r][1] : aregs[s & 1][r][0]);
      *(bf16x8*)&sab[n * BK + (sak ^ ((n & 7) << 3))] = v;
    }
    __syncthreads();

    // ---- issue loads for step s+2 into reg set s&1 (depth-2 cover) ----
    if (s + 2 < NSTEP) {
      const float* wp2 = wp + (s + 2) * BK;
      const float* ap2 = ap + (size_t)(s + 2) * BK * L_DIM;
#pragma unroll
      for (int j = 0; j < 4; ++j)
        wregs[s & 1][j] = wok ? *(const f32x4*)(wp2 + 4 * j)
                              : (f32x4){0.f, 0.f, 0.f, 0.f};
#pragma unroll
      for (int r = 0; r < 8; ++r)
        aregs[s & 1][r] = *(const f32x2*)(ap2 + (size_t)r * L_DIM);
    }

    // ---- compute from LDS buffer s&1 ----
#pragma unroll
    for (int kk = 0; kk < BK; kk += 32) {
      bf16x8 wf[4], af[2];
#pragma unroll
      for (int mt = 0; mt < 4; ++mt) {
        int m = mg * 64 + mt * 16 + l15;
        wf[mt] = *(const bf16x8*)&swb[m * BK + ((kk + lk8) ^ ((m & 7) << 3))];
      }
#pragma unroll
      for (int nt = 0; nt < 2; ++nt) {
        int n = ng * 32 + nt * 16 + l15;
        af[nt] = *(const bf16x8*)&sab[n * BK + ((kk + lk8) ^ ((n & 7) << 3))];
      }
#pragma unroll
      for (int mt = 0; mt < 4; ++mt)
#pragma unroll
        for (int nt = 0; nt < 2; ++nt)
          acc[mt][nt] = __builtin_amdgcn_mfma_f32_16x16x32_bf16(
              wf[mt], af[nt], acc[mt][nt], 0, 0, 0);
    }
    // single barrier/step: next iteration writes the other LDS buffer
  }

  // ---- store transposed bf16 partials: part[kc][n][m] ----
  unsigned short* pb = part + (size_t)kc * PART_KC;
#pragma unroll
  for (int mt = 0; mt < 4; ++mt) {
    const int m0 = m0b + mg * 64 + mt * 16 + (lane >> 4) * 4;
#pragma unroll
    for (int nt = 0; nt < 2; ++nt) {
      const int n = n0b + ng * 32 + nt * 16 + l15;
      bf16x4 v;
      v[0] = (short)f2bf(acc[mt][nt][0]);
      v[1] = (short)f2bf(acc[mt][nt][1]);
      v[2] = (short)f2bf(acc[mt][nt][2]);
      v[3] = (short)f2bf(acc[mt][nt][3]);
      *(bf16x4*)&pb[(size_t)n * MSTRIDE + m0] = v;
    }
  }

  // ---- publish partials; last contributor per n-tile reduces ----
  __threadfence();                      // release this block's stores
  __syncthreads();
  if (t == 0)
    s_old = __hip_atomic_fetch_add(&ctrs[nt8], 1, __ATOMIC_ACQ_REL,
                                   __HIP_MEMORY_SCOPE_AGENT);
  __syncthreads();
  if (s_old != CONTRIB - 1) return;     // not last -> done (no spinning)

  // Reducer: 512 thr = 2 col-pairs x 256 m. Reads ~1MB (L2-hot).
  {
    const int tm   = t & 255;           // m index
    const int pair = t >> 8;            // 0/1: column half
    const int w4i  = (t >> 6) & 3;      // wave within pair
    const float bias = (tm < C2) ? b3[tm] : 0.f;
    const float w4v  = (tm < C2) ? w4[tm] : 0.f;

    for (int c = 0; c < 64; ++c) {
      const int n = n0b + pair * 64 + c;
      const unsigned short* p = part + (size_t)n * MSTRIDE + tm;
      float ssum = 0.f;
#pragma unroll
      for (int kc2 = 0; kc2 < KSPLIT; ++kc2)
        ssum += bf2f(p[(size_t)kc2 * PART_KC]);
      float e  = fmaxf(ssum + bias, 0.f);
      float c4 = w4v * e;
#pragma unroll
      for (int off = 32; off; off >>= 1) {
        e  += __shfl_xor(e, off);
        c4 += __shfl_xor(c4, off);
      }
      if (lane == 0) { red[0][pair][w4i] = e; red[1][pair][w4i] = c4; }
      __syncthreads();
      if ((t & 255) == 0) {
        const float cs  = red[0][pair][0] + red[0][pair][1] +
                          red[0][pair][2] + red[0][pair][3];
        const float tc4 = red[1][pair][0] + red[1][pair][1] +
                          red[1][pair][2] + red[1][pair][3] + b4[0];
        const float mask = 1.f / (1.f + expf(-tc4));
        colbuf[n] = cs * (1.f + mask) * (1.f / (float)L_DIM);
      }
      __syncthreads();
    }
  }
}

// ---------------- Stage 2: broadcast to all nodes (fully coalesced) --------
__global__ __launch_bounds__(256) void k_broadcast(
    const float* __restrict__ colbuf, float4* __restrict__ out)
{
  const size_t idx = (size_t)blockIdx.x * 256 + threadIdx.x;  // float4 index
  const int nq = (int)(idx & 255);
  const float4 v = *(const float4*)(colbuf + nq * 4);
  out[idx] = v;
}

extern "C" void kernel_launch(void* const* d_in, const int* in_sizes, int n_in,
                              void* d_out, int out_size, void* d_ws, size_t ws_size,
                              hipStream_t stream) {
  // inputs: x, edge_index, edge_attr, conv3_w, conv3_b, conv4_w, conv4_b
  const float* edge_attr = (const float*)d_in[2];   // [8192][1024]
  const float* w3        = (const float*)d_in[3];   // [240][8192]
  const float* b3        = (const float*)d_in[4];   // [240]
  const float* w4        = (const float*)d_in[5];   // [240]
  const float* b4        = (const float*)d_in[6];   // [1]

  // d_ws layout: part (8.4MB) | colbuf[1024] f32 | ctrs[8] int
  unsigned short* part = (unsigned short*)d_ws;
  float* colbuf = (float*)((char*)d_ws + PART_BYTES);
  int* ctrs     = (int*)((char*)d_ws + PART_BYTES + 4096);

  hipMemsetAsync(ctrs, 0, 64, stream);
  k_gemm_red  <<<dim3(256),   512, 0, stream>>>(w3, edge_attr, b3, w4, b4,
                                                part, colbuf, ctrs);
  k_broadcast <<<dim3(10000), 256, 0, stream>>>(colbuf, (float4*)d_out);
}

// Round 10
// 38.539 us; speedup vs baseline: 4.5615x; 4.5615x over previous
//
#include <hip/hip_runtime.h>
#include <hip/hip_bf16.h>

#define K_DIM 8192
#define L_DIM 1024
#define C2 240
#define MSTRIDE 256                 // padded m stride in partials
#define BM 128
#define BN 128
#define BK 64
#define KSPLIT 32
#define KCHUNK 256                  // K_DIM / KSPLIT
#define NSTEP 4                     // KCHUNK / BK
#define PART_KC (L_DIM * MSTRIDE)   // 262144 bf16 elems per k-chunk
#define PART_BYTES ((size_t)KSPLIT * PART_KC * 2)  // 16,777,216
#define TOT_F4 (10000 * 256)

typedef __attribute__((ext_vector_type(4))) float f32x4;
typedef __attribute__((ext_vector_type(2))) float f32x2;
typedef __attribute__((ext_vector_type(8))) short bf16x8;
typedef __attribute__((ext_vector_type(4))) short bf16x4;

__device__ __forceinline__ unsigned short f2bf(float f) {
  return __builtin_bit_cast(unsigned short, __float2bfloat16(f));
}
__device__ __forceinline__ float bf2f(unsigned short h) {
  unsigned u = ((unsigned)h) << 16;
  return __builtin_bit_cast(float, u);
}

// ---------------- Stage 1: bf16 MFMA K-split GEMM --------------------------
// part[kc][n][m(pad 256)] = (W[240][8192] @ A[8192][1024]) k-chunk partials.
// 512 blocks x 512 thr (8 waves: 2m x 4n of 64x32) -> 2 blocks/CU
// (LDS 64.5KB x2 = 129KB <= 160KB; VGPR 72 <= 128) so barrier drains of one
// block hide under the other's compute. R8 body, KSPLIT 16->32.
// NO device-scope fences/atomics: measured ~0.66us EACH, serialized (R5/R9).
__global__ __launch_bounds__(512, 4) void k_gemm(
    const float* __restrict__ Wm, const float* __restrict__ Am,
    unsigned short* __restrict__ part)
{
  __shared__ __align__(16) unsigned short sW[2 * BM * BK];  // 32 KB dbuf
  __shared__ __align__(16) unsigned short sA[2 * BN * BK];  // 32 KB dbuf

  const int t    = threadIdx.x;
  const int lane = t & 63;
  const int bid  = blockIdx.x;

  // XCD-chunked remap (bijective, 512 % 8 == 0): XCD owns 4 kc x all tiles.
  const int wk    = (bid & 7) * 64 + (bid >> 3);
  const int nt8   = wk & 7;
  const int mtile = (wk >> 3) & 1;
  const int kc    = wk >> 4;            // 0..31

  const int wid = t >> 6;
  const int mg  = wid >> 2;       // 2 groups of 64 m
  const int ng  = wid & 3;        // 4 groups of 32 n
  const int l15 = lane & 15;
  const int lk8 = (lane >> 4) * 8;

  const int n0b = nt8 * BN;
  const int m0b = mtile * BM;
  const int k0  = kc * KCHUNK;

  // W staging: thread -> (row t>>2, 16 k at (t&3)*16); 4 f32x4 loads.
  const int swm = t >> 2;
  const int swk = (t & 3) * 16;
  // A staging: thread -> (2 cols at 2*(t&63), 8 k at wid*8); 8 f32x2 loads.
  const int san = (t & 63) * 2;
  const int sak = (t >> 6) * 8;

  const float* wp = Wm + (size_t)(m0b + swm) * K_DIM + k0 + swk;
  const float* ap = Am + (size_t)(k0 + sak) * L_DIM + n0b + san;
  const bool wok = (m0b + swm) < C2;

  f32x4 wregs[2][4];
  f32x2 aregs[2][8];
  f32x4 acc[4][2];
#pragma unroll
  for (int i = 0; i < 4; ++i)
#pragma unroll
    for (int j = 0; j < 2; ++j) acc[i][j] = (f32x4){0.f, 0.f, 0.f, 0.f};

  // prologue: issue loads for steps 0 and 1 (depth-2)
#pragma unroll
  for (int p = 0; p < 2; ++p) {
#pragma unroll
    for (int j = 0; j < 4; ++j)
      wregs[p][j] = wok ? *(const f32x4*)(wp + p * BK + 4 * j)
                        : (f32x4){0.f, 0.f, 0.f, 0.f};
#pragma unroll
    for (int r = 0; r < 8; ++r)
      aregs[p][r] = *(const f32x2*)(ap + (size_t)(p * BK + r) * L_DIM);
  }

#pragma unroll
  for (int s = 0; s < NSTEP; ++s) {
    unsigned short* swb = sW + (s & 1) * (BM * BK);
    unsigned short* sab = sA + (s & 1) * (BN * BK);

    // ---- convert + swizzled LDS write from reg set s&1 ----
#pragma unroll
    for (int j = 0; j < 2; ++j) {       // two bf16x8 per thread (16 k)
      f32x4 a = wregs[s & 1][2 * j], b = wregs[s & 1][2 * j + 1];
      bf16x8 v;
      v[0] = (short)f2bf(a[0]); v[1] = (short)f2bf(a[1]);
      v[2] = (short)f2bf(a[2]); v[3] = (short)f2bf(a[3]);
      v[4] = (short)f2bf(b[0]); v[5] = (short)f2bf(b[1]);
      v[6] = (short)f2bf(b[2]); v[7] = (short)f2bf(b[3]);
      *(bf16x8*)&swb[swm * BK + ((swk + 8 * j) ^ ((swm & 7) << 3))] = v;
    }
#pragma unroll
    for (int j = 0; j < 2; ++j) {       // two cols, 8 k each
      const int n = san + j;
      bf16x8 v;
#pragma unroll
      for (int r = 0; r < 8; ++r)
        v[r] = (short)f2bf(j ? aregs[s & 1][r][1] : aregs[s & 1][r][0]);
      *(bf16x8*)&sab[n * BK + (sak ^ ((n & 7) << 3))] = v;
    }
    __syncthreads();

    // ---- issue loads for step s+2 into reg set s&1 (depth-2 cover) ----
    if (s + 2 < NSTEP) {
      const float* wp2 = wp + (s + 2) * BK;
      const float* ap2 = ap + (size_t)(s + 2) * BK * L_DIM;
#pragma unroll
      for (int j = 0; j < 4; ++j)
        wregs[s & 1][j] = wok ? *(const f32x4*)(wp2 + 4 * j)
                              : (f32x4){0.f, 0.f, 0.f, 0.f};
#pragma unroll
      for (int r = 0; r < 8; ++r)
        aregs[s & 1][r] = *(const f32x2*)(ap2 + (size_t)r * L_DIM);
    }

    // ---- compute from LDS buffer s&1 ----
#pragma unroll
    for (int kk = 0; kk < BK; kk += 32) {
      bf16x8 wf[4], af[2];
#pragma unroll
      for (int mt = 0; mt < 4; ++mt) {
        int m = mg * 64 + mt * 16 + l15;
        wf[mt] = *(const bf16x8*)&swb[m * BK + ((kk + lk8) ^ ((m & 7) << 3))];
      }
#pragma unroll
      for (int nt = 0; nt < 2; ++nt) {
        int n = ng * 32 + nt * 16 + l15;
        af[nt] = *(const bf16x8*)&sab[n * BK + ((kk + lk8) ^ ((n & 7) << 3))];
      }
#pragma unroll
      for (int mt = 0; mt < 4; ++mt)
#pragma unroll
        for (int nt = 0; nt < 2; ++nt)
          acc[mt][nt] = __builtin_amdgcn_mfma_f32_16x16x32_bf16(
              wf[mt], af[nt], acc[mt][nt], 0, 0, 0);
    }
    // single barrier/step: next iteration writes the other LDS buffer
  }

  // ---- store transposed bf16 partials: part[kc][n][m] ----
  unsigned short* pb = part + (size_t)kc * PART_KC;
#pragma unroll
  for (int mt = 0; mt < 4; ++mt) {
    const int m0 = m0b + mg * 64 + mt * 16 + (lane >> 4) * 4;
#pragma unroll
    for (int nt = 0; nt < 2; ++nt) {
      const int n = n0b + ng * 32 + nt * 16 + l15;
      bf16x4 v;
      v[0] = (short)f2bf(acc[mt][nt][0]);
      v[1] = (short)f2bf(acc[mt][nt][1]);
      v[2] = (short)f2bf(acc[mt][nt][2]);
      v[3] = (short)f2bf(acc[mt][nt][3]);
      *(bf16x4*)&pb[(size_t)n * MSTRIDE + m0] = v;
    }
  }
}

// ---------------- Stage 2: kc-reduce + bias + ReLU + m-reductions ----------
// One block per column n: thread t = m (coalesced 2B reads across t).
__global__ __launch_bounds__(256) void k_colbuf(
    const unsigned short* __restrict__ part, const float* __restrict__ b3,
    const float* __restrict__ w4, const float* __restrict__ b4,
    float* __restrict__ colbuf)
{
  __shared__ float red[2][4];
  const int n = blockIdx.x;
  const int t = threadIdx.x;
  const unsigned short* p = part + (size_t)n * MSTRIDE + t;
  float s = 0.f;
#pragma unroll
  for (int kcc = 0; kcc < KSPLIT; ++kcc)
    s += bf2f(p[(size_t)kcc * PART_KC]);
  float e = 0.f, c4 = 0.f;
  if (t < C2) {
    e  = fmaxf(s + b3[t], 0.f);
    c4 = w4[t] * e;
  }
#pragma unroll
  for (int off = 32; off; off >>= 1) {
    e  += __shfl_xor(e, off);
    c4 += __shfl_xor(c4, off);
  }
  const int wv = t >> 6;
  if ((t & 63) == 0) { red[0][wv] = e; red[1][wv] = c4; }
  __syncthreads();
  if (t == 0) {
    const float cs  = red[0][0] + red[0][1] + red[0][2] + red[0][3];
    const float tc4 = red[1][0] + red[1][1] + red[1][2] + red[1][3] + b4[0];
    const float mask = 1.f / (1.f + expf(-tc4));
    colbuf[n] = cs * (1.f + mask) * (1.f / (float)L_DIM);
  }
}

// ---------------- Stage 3: broadcast to all nodes (fully coalesced) --------
__global__ __launch_bounds__(256) void k_broadcast(
    const float* __restrict__ colbuf, float4* __restrict__ out)
{
  const size_t idx = (size_t)blockIdx.x * 256 + threadIdx.x;  // float4 index
  const int nq = (int)(idx & 255);
  const float4 v = *(const float4*)(colbuf + nq * 4);
  out[idx] = v;
}

extern "C" void kernel_launch(void* const* d_in, const int* in_sizes, int n_in,
                              void* d_out, int out_size, void* d_ws, size_t ws_size,
                              hipStream_t stream) {
  // inputs: x, edge_index, edge_attr, conv3_w, conv3_b, conv4_w, conv4_b
  const float* edge_attr = (const float*)d_in[2];   // [8192][1024]
  const float* w3        = (const float*)d_in[3];   // [240][8192]
  const float* b3        = (const float*)d_in[4];   // [240]
  const float* w4        = (const float*)d_in[5];   // [240]
  const float* b4        = (const float*)d_in[6];   // [1]

  float* out = (float*)d_out;

  // partials in d_ws (measured ws_size ~268MB >> 16.8MB); colbuf after them.
  unsigned short* part;
  float* colbuf;
  if (ws_size >= PART_BYTES + 4096) {
    part   = (unsigned short*)d_ws;
    colbuf = (float*)((char*)d_ws + PART_BYTES);
  } else {
    part   = (unsigned short*)d_out;   // overwritten by broadcast afterwards
    colbuf = (float*)d_ws;
  }

  k_gemm      <<<dim3(512),   512, 0, stream>>>(w3, edge_attr, part);
  k_colbuf    <<<dim3(1024),  256, 0, stream>>>(part, b3, w4, b4, colbuf);
  k_broadcast <<<dim3(10000), 256, 0, stream>>>(colbuf, (float4*)out);
}

// Round 11
// 32.973 us; speedup vs baseline: 5.3315x; 1.1688x over previous
//
#include <hip/hip_runtime.h>
#include <hip/hip_bf16.h>

#define K_DIM 8192
#define L_DIM 1024
#define C2 240
#define MSTRIDE 256                 // padded m stride in partials
#define BM 128
#define BN 128
#define BK 64
#define KSPLIT 16
#define KCHUNK 512                  // K_DIM / KSPLIT
#define NSTEP 8                     // KCHUNK / BK
#define PART_KC (L_DIM * MSTRIDE)   // 262144 bf16 elems per k-chunk
#define PART_BYTES ((size_t)KSPLIT * PART_KC * 2)  // 8,388,608
#define TOT_F4 (10000 * 256)        // 2,560,000 float4 outputs
#define BCAST_BLK 2048              // grid-stride broadcast (8 blocks/CU)

typedef __attribute__((ext_vector_type(4))) float f32x4;
typedef __attribute__((ext_vector_type(2))) float f32x2;
typedef __attribute__((ext_vector_type(8))) short bf16x8;
typedef __attribute__((ext_vector_type(4))) short bf16x4;

__device__ __forceinline__ unsigned short f2bf(float f) {
  return __builtin_bit_cast(unsigned short, __float2bfloat16(f));
}
__device__ __forceinline__ float bf2f(unsigned short h) {
  unsigned u = ((unsigned)h) << 16;
  return __builtin_bit_cast(float, u);
}

// ---------------- Stage 1: bf16 MFMA K-split GEMM (R8 body, proven) --------
// part[kc][n][m(pad 256)] = (W[240][8192] @ A[8192][1024]) k-chunk partials.
// 256 blocks x 512 thr (8 waves: 2m x 4n of 64x32). KSPLIT=16, NSTEP=8,
// depth-2 register prefetch + double-buffered LDS, single barrier/step.
// R10 lesson: 2 blocks/CU via KSPLIT=32 LOSES (traffic x2, pipeline x1/2).
__global__ __launch_bounds__(512, 2) void k_gemm(
    const float* __restrict__ Wm, const float* __restrict__ Am,
    unsigned short* __restrict__ part)
{
  __shared__ __align__(16) unsigned short sW[2 * BM * BK];  // 32 KB dbuf
  __shared__ __align__(16) unsigned short sA[2 * BN * BK];  // 32 KB dbuf

  const int t    = threadIdx.x;
  const int lane = t & 63;
  const int bid  = blockIdx.x;

  // XCD-chunked remap (bijective, 256 % 8 == 0): XCD owns 2 kc x all tiles.
  const int wk    = (bid & 7) * 32 + (bid >> 3);
  const int nt8   = wk & 7;
  const int mtile = (wk >> 3) & 1;
  const int kc    = wk >> 4;            // 0..15

  const int wid = t >> 6;
  const int mg  = wid >> 2;       // 2 groups of 64 m
  const int ng  = wid & 3;        // 4 groups of 32 n
  const int l15 = lane & 15;
  const int lk8 = (lane >> 4) * 8;

  const int n0b = nt8 * BN;
  const int m0b = mtile * BM;
  const int k0  = kc * KCHUNK;

  // W staging: thread -> (row t>>2, 16 k at (t&3)*16); 4 f32x4 loads.
  const int swm = t >> 2;
  const int swk = (t & 3) * 16;
  // A staging: thread -> (2 cols at 2*(t&63), 8 k at wid*8); 8 f32x2 loads.
  const int san = (t & 63) * 2;
  const int sak = (t >> 6) * 8;

  const float* wp = Wm + (size_t)(m0b + swm) * K_DIM + k0 + swk;
  const float* ap = Am + (size_t)(k0 + sak) * L_DIM + n0b + san;
  const bool wok = (m0b + swm) < C2;

  f32x4 wregs[2][4];
  f32x2 aregs[2][8];
  f32x4 acc[4][2];
#pragma unroll
  for (int i = 0; i < 4; ++i)
#pragma unroll
    for (int j = 0; j < 2; ++j) acc[i][j] = (f32x4){0.f, 0.f, 0.f, 0.f};

  // prologue: issue loads for steps 0 and 1 (depth-2)
#pragma unroll
  for (int p = 0; p < 2; ++p) {
#pragma unroll
    for (int j = 0; j < 4; ++j)
      wregs[p][j] = wok ? *(const f32x4*)(wp + p * BK + 4 * j)
                        : (f32x4){0.f, 0.f, 0.f, 0.f};
#pragma unroll
    for (int r = 0; r < 8; ++r)
      aregs[p][r] = *(const f32x2*)(ap + (size_t)(p * BK + r) * L_DIM);
  }

#pragma unroll
  for (int s = 0; s < NSTEP; ++s) {
    unsigned short* swb = sW + (s & 1) * (BM * BK);
    unsigned short* sab = sA + (s & 1) * (BN * BK);

    // ---- convert + swizzled LDS write from reg set s&1 ----
#pragma unroll
    for (int j = 0; j < 2; ++j) {       // two bf16x8 per thread (16 k)
      f32x4 a = wregs[s & 1][2 * j], b = wregs[s & 1][2 * j + 1];
      bf16x8 v;
      v[0] = (short)f2bf(a[0]); v[1] = (short)f2bf(a[1]);
      v[2] = (short)f2bf(a[2]); v[3] = (short)f2bf(a[3]);
      v[4] = (short)f2bf(b[0]); v[5] = (short)f2bf(b[1]);
      v[6] = (short)f2bf(b[2]); v[7] = (short)f2bf(b[3]);
      *(bf16x8*)&swb[swm * BK + ((swk + 8 * j) ^ ((swm & 7) << 3))] = v;
    }
#pragma unroll
    for (int j = 0; j < 2; ++j) {       // two cols, 8 k each
      const int n = san + j;
      bf16x8 v;
#pragma unroll
      for (int r = 0; r < 8; ++r)
        v[r] = (short)f2bf(j ? aregs[s & 1][r][1] : aregs[s & 1][r][0]);
      *(bf16x8*)&sab[n * BK + (sak ^ ((n & 7) << 3))] = v;
    }
    __syncthreads();

    // ---- issue loads for step s+2 into reg set s&1 (depth-2 cover) ----
    if (s + 2 < NSTEP) {
      const float* wp2 = wp + (s + 2) * BK;
      const float* ap2 = ap + (size_t)(s + 2) * BK * L_DIM;
#pragma unroll
      for (int j = 0; j < 4; ++j)
        wregs[s & 1][j] = wok ? *(const f32x4*)(wp2 + 4 * j)
                              : (f32x4){0.f, 0.f, 0.f, 0.f};
#pragma unroll
      for (int r = 0; r < 8; ++r)
        aregs[s & 1][r] = *(const f32x2*)(ap2 + (size_t)r * L_DIM);
    }

    // ---- compute from LDS buffer s&1 (setprio: favor MFMA waves) ----
    __builtin_amdgcn_s_setprio(1);
#pragma unroll
    for (int kk = 0; kk < BK; kk += 32) {
      bf16x8 wf[4], af[2];
#pragma unroll
      for (int mt = 0; mt < 4; ++mt) {
        int m = mg * 64 + mt * 16 + l15;
        wf[mt] = *(const bf16x8*)&swb[m * BK + ((kk + lk8) ^ ((m & 7) << 3))];
      }
#pragma unroll
      for (int nt = 0; nt < 2; ++nt) {
        int n = ng * 32 + nt * 16 + l15;
        af[nt] = *(const bf16x8*)&sab[n * BK + ((kk + lk8) ^ ((n & 7) << 3))];
      }
#pragma unroll
      for (int mt = 0; mt < 4; ++mt)
#pragma unroll
        for (int nt = 0; nt < 2; ++nt)
          acc[mt][nt] = __builtin_amdgcn_mfma_f32_16x16x32_bf16(
              wf[mt], af[nt], acc[mt][nt], 0, 0, 0);
    }
    __builtin_amdgcn_s_setprio(0);
    // single barrier/step: next iteration writes the other LDS buffer
  }

  // ---- store transposed bf16 partials: part[kc][n][m] ----
  unsigned short* pb = part + (size_t)kc * PART_KC;
#pragma unroll
  for (int mt = 0; mt < 4; ++mt) {
    const int m0 = m0b + mg * 64 + mt * 16 + (lane >> 4) * 4;
#pragma unroll
    for (int nt = 0; nt < 2; ++nt) {
      const int n = n0b + ng * 32 + nt * 16 + l15;
      bf16x4 v;
      v[0] = (short)f2bf(acc[mt][nt][0]);
      v[1] = (short)f2bf(acc[mt][nt][1]);
      v[2] = (short)f2bf(acc[mt][nt][2]);
      v[3] = (short)f2bf(acc[mt][nt][3]);
      *(bf16x4*)&pb[(size_t)n * MSTRIDE + m0] = v;
    }
  }
}

// ---------------- Stage 2: kc-reduce + bias + ReLU + m-reductions ----------
// 512 blocks x 2 columns each: thread t = m (coalesced 2B reads across t).
__global__ __launch_bounds__(256) void k_colbuf(
    const unsigned short* __restrict__ part, const float* __restrict__ b3,
    const float* __restrict__ w4, const float* __restrict__ b4,
    float* __restrict__ colbuf)
{
  __shared__ float red[2][4];
  const int t  = threadIdx.x;
  const int wv = t >> 6;
  const float bias = (t < C2) ? b3[t] : 0.f;
  const float w4v  = (t < C2) ? w4[t] : 0.f;

#pragma unroll
  for (int half = 0; half < 2; ++half) {
    const int n = blockIdx.x * 2 + half;
    const unsigned short* p = part + (size_t)n * MSTRIDE + t;
    float s = 0.f;
#pragma unroll
    for (int kcc = 0; kcc < KSPLIT; ++kcc)
      s += bf2f(p[(size_t)kcc * PART_KC]);
    float e  = (t < C2) ? fmaxf(s + bias, 0.f) : 0.f;
    float c4 = w4v * e;
#pragma unroll
    for (int off = 32; off; off >>= 1) {
      e  += __shfl_xor(e, off);
      c4 += __shfl_xor(c4, off);
    }
    if ((t & 63) == 0) { red[0][wv] = e; red[1][wv] = c4; }
    __syncthreads();
    if (t == 0) {
      const float cs  = red[0][0] + red[0][1] + red[0][2] + red[0][3];
      const float tc4 = red[1][0] + red[1][1] + red[1][2] + red[1][3] + b4[0];
      const float mask = 1.f / (1.f + expf(-tc4));
      colbuf[n] = cs * (1.f + mask) * (1.f / (float)L_DIM);
    }
    __syncthreads();
  }
}

// ---------------- Stage 3: broadcast, grid-stride (G11: cap ~2048 blocks) --
// stride = 2048*256 float4s; (i % 256) == t invariant -> value loaded once.
__global__ __launch_bounds__(256) void k_broadcast(
    const float* __restrict__ colbuf, float4* __restrict__ out)
{
  const int t = threadIdx.x;
  const float4 v = *(const float4*)(colbuf + t * 4);
  for (size_t i = (size_t)blockIdx.x * 256 + t; i < TOT_F4;
       i += (size_t)BCAST_BLK * 256)
    out[i] = v;
}

extern "C" void kernel_launch(void* const* d_in, const int* in_sizes, int n_in,
                              void* d_out, int out_size, void* d_ws, size_t ws_size,
                              hipStream_t stream) {
  // inputs: x, edge_index, edge_attr, conv3_w, conv3_b, conv4_w, conv4_b
  const float* edge_attr = (const float*)d_in[2];   // [8192][1024]
  const float* w3        = (const float*)d_in[3];   // [240][8192]
  const float* b3        = (const float*)d_in[4];   // [240]
  const float* w4        = (const float*)d_in[5];   // [240]
  const float* b4        = (const float*)d_in[6];   // [1]

  float* out = (float*)d_out;

  // partials in d_ws (measured ws_size ~268MB >> 8.4MB); colbuf after them.
  unsigned short* part;
  float* colbuf;
  if (ws_size >= PART_BYTES + 4096) {
    part   = (unsigned short*)d_ws;
    colbuf = (float*)((char*)d_ws + PART_BYTES);
  } else {
    part   = (unsigned short*)d_out;   // overwritten by broadcast afterwards
    colbuf = (float*)d_ws;
  }

  k_gemm      <<<dim3(256),       512, 0, stream>>>(w3, edge_attr, part);
  k_colbuf    <<<dim3(512),       256, 0, stream>>>(part, b3, w4, b4, colbuf);
  k_broadcast <<<dim3(BCAST_BLK), 256, 0, stream>>>(colbuf, (float4*)out);
}

// Round 12
// 31.975 us; speedup vs baseline: 5.4980x; 1.0312x over previous
//
#include <hip/hip_runtime.h>
#include <hip/hip_bf16.h>

#define K_DIM 8192
#define L_DIM 1024
#define C2 240
#define MSTRIDE 256                 // padded m stride in partials
#define BM 64
#define BN 128
#define BK 64
#define KSPLIT 16
#define KCHUNK 512                  // K_DIM / KSPLIT
#define NSTEP 8                     // KCHUNK / BK
#define PART_KC (L_DIM * MSTRIDE)   // 262144 bf16 elems per k-chunk
#define PART_BYTES ((size_t)KSPLIT * PART_KC * 2)  // 8,388,608
#define TOT_F4 (10000 * 256)

typedef __attribute__((ext_vector_type(4))) float f32x4;
typedef __attribute__((ext_vector_type(2))) float f32x2;
typedef __attribute__((ext_vector_type(8))) short bf16x8;
typedef __attribute__((ext_vector_type(4))) short bf16x4;

__device__ __forceinline__ unsigned short f2bf(float f) {
  return __builtin_bit_cast(unsigned short, __float2bfloat16(f));
}
__device__ __forceinline__ float bf2f(unsigned short h) {
  unsigned u = ((unsigned)h) << 16;
  return __builtin_bit_cast(float, u);
}

// ---------------- Stage 1: bf16 MFMA K-split GEMM --------------------------
// part[kc][n][m(pad 256)] = (W[240][8192] @ A[8192][1024]) k-chunk partials.
// BM=64 x BN=128: grid = 4 mtiles x 8 ntiles x 16 kc = 512 blocks x 512 thr,
// LDS 48KB -> 2 blocks/CU CO-RESIDENT (the R10 retest, now traffic-neutral:
// unique HBM bytes and partials identical to R8's BM=128 config).
// 8 waves: 2 m-groups x 4 n-groups of 32x32; depth-2 reg prefetch; dbuf LDS;
// one barrier/step. No device-scope fences (R5/R9: ~0.66us each, serial).
__global__ __launch_bounds__(512, 4) void k_gemm(
    const float* __restrict__ Wm, const float* __restrict__ Am,
    unsigned short* __restrict__ part)
{
  __shared__ __align__(16) unsigned short sW[2 * BM * BK];  // 16 KB dbuf
  __shared__ __align__(16) unsigned short sA[2 * BN * BK];  // 32 KB dbuf

  const int t    = threadIdx.x;
  const int lane = t & 63;
  const int bid  = blockIdx.x;

  // XCD-chunked remap (bijective, 512 % 8 == 0): XCD owns 2 kc x all tiles.
  const int wk    = (bid & 7) * 64 + (bid >> 3);
  const int nt8   = wk & 7;
  const int mtile = (wk >> 3) & 3;      // 4 m-tiles of 64
  const int kc    = wk >> 5;            // 0..15

  const int wid = t >> 6;
  const int mg  = wid >> 2;       // 2 groups of 32 m
  const int ng  = wid & 3;        // 4 groups of 32 n
  const int l15 = lane & 15;
  const int lk8 = (lane >> 4) * 8;

  const int n0b = nt8 * BN;
  const int m0b = mtile * BM;
  const int k0  = kc * KCHUNK;

  // W staging: thread -> (row t>>3, 8 k at (t&7)*8); 2 f32x4 loads.
  const int swm = t >> 3;
  const int swk = (t & 7) * 8;
  // A staging: thread -> (2 cols at 2*(t&63), 8 k at wid*8); 8 f32x2 loads.
  const int san = (t & 63) * 2;
  const int sak = (t >> 6) * 8;

  const float* wp = Wm + (size_t)(m0b + swm) * K_DIM + k0 + swk;
  const float* ap = Am + (size_t)(k0 + sak) * L_DIM + n0b + san;
  const bool wok = (m0b + swm) < C2;

  f32x4 wregs[2][2];
  f32x2 aregs[2][8];
  f32x4 acc[2][2];
#pragma unroll
  for (int i = 0; i < 2; ++i)
#pragma unroll
    for (int j = 0; j < 2; ++j) acc[i][j] = (f32x4){0.f, 0.f, 0.f, 0.f};

  // prologue: issue loads for steps 0 and 1 (depth-2)
#pragma unroll
  for (int p = 0; p < 2; ++p) {
#pragma unroll
    for (int j = 0; j < 2; ++j)
      wregs[p][j] = wok ? *(const f32x4*)(wp + p * BK + 4 * j)
                        : (f32x4){0.f, 0.f, 0.f, 0.f};
#pragma unroll
    for (int r = 0; r < 8; ++r)
      aregs[p][r] = *(const f32x2*)(ap + (size_t)(p * BK + r) * L_DIM);
  }

#pragma unroll
  for (int s = 0; s < NSTEP; ++s) {
    unsigned short* swb = sW + (s & 1) * (BM * BK);
    unsigned short* sab = sA + (s & 1) * (BN * BK);

    // ---- convert + swizzled LDS write from reg set s&1 ----
    {
      f32x4 a = wregs[s & 1][0], b = wregs[s & 1][1];
      bf16x8 v;
      v[0] = (short)f2bf(a[0]); v[1] = (short)f2bf(a[1]);
      v[2] = (short)f2bf(a[2]); v[3] = (short)f2bf(a[3]);
      v[4] = (short)f2bf(b[0]); v[5] = (short)f2bf(b[1]);
      v[6] = (short)f2bf(b[2]); v[7] = (short)f2bf(b[3]);
      *(bf16x8*)&swb[swm * BK + (swk ^ ((swm & 7) << 3))] = v;
    }
#pragma unroll
    for (int j = 0; j < 2; ++j) {       // two cols, 8 k each
      const int n = san + j;
      bf16x8 v;
#pragma unroll
      for (int r = 0; r < 8; ++r)
        v[r] = (short)f2bf(j ? aregs[s & 1][r][1] : aregs[s & 1][r][0]);
      *(bf16x8*)&sab[n * BK + (sak ^ ((n & 7) << 3))] = v;
    }
    __syncthreads();

    // ---- issue loads for step s+2 into reg set s&1 (depth-2 cover) ----
    if (s + 2 < NSTEP) {
      const float* wp2 = wp + (s + 2) * BK;
      const float* ap2 = ap + (size_t)(s + 2) * BK * L_DIM;
#pragma unroll
      for (int j = 0; j < 2; ++j)
        wregs[s & 1][j] = wok ? *(const f32x4*)(wp2 + 4 * j)
                              : (f32x4){0.f, 0.f, 0.f, 0.f};
#pragma unroll
      for (int r = 0; r < 8; ++r)
        aregs[s & 1][r] = *(const f32x2*)(ap2 + (size_t)r * L_DIM);
    }

    // ---- compute from LDS buffer s&1 ----
#pragma unroll
    for (int kk = 0; kk < BK; kk += 32) {
      bf16x8 wf[2], af[2];
#pragma unroll
      for (int mt = 0; mt < 2; ++mt) {
        int m = mg * 32 + mt * 16 + l15;
        wf[mt] = *(const bf16x8*)&swb[m * BK + ((kk + lk8) ^ ((m & 7) << 3))];
      }
#pragma unroll
      for (int nt = 0; nt < 2; ++nt) {
        int n = ng * 32 + nt * 16 + l15;
        af[nt] = *(const bf16x8*)&sab[n * BK + ((kk + lk8) ^ ((n & 7) << 3))];
      }
#pragma unroll
      for (int mt = 0; mt < 2; ++mt)
#pragma unroll
        for (int nt = 0; nt < 2; ++nt)
          acc[mt][nt] = __builtin_amdgcn_mfma_f32_16x16x32_bf16(
              wf[mt], af[nt], acc[mt][nt], 0, 0, 0);
    }
    // single barrier/step: next iteration writes the other LDS buffer;
    // writes to THIS buffer recur only after the next barrier (safe).
  }

  // ---- store transposed bf16 partials: part[kc][n][m] ----
  unsigned short* pb = part + (size_t)kc * PART_KC;
#pragma unroll
  for (int mt = 0; mt < 2; ++mt) {
    const int m0 = m0b + mg * 32 + mt * 16 + (lane >> 4) * 4;
#pragma unroll
    for (int nt = 0; nt < 2; ++nt) {
      const int n = n0b + ng * 32 + nt * 16 + l15;
      bf16x4 v;
      v[0] = (short)f2bf(acc[mt][nt][0]);
      v[1] = (short)f2bf(acc[mt][nt][1]);
      v[2] = (short)f2bf(acc[mt][nt][2]);
      v[3] = (short)f2bf(acc[mt][nt][3]);
      *(bf16x4*)&pb[(size_t)n * MSTRIDE + m0] = v;
    }
  }
}

// ---------------- Stage 2: kc-reduce + bias + ReLU + m-reductions ----------
// One block per column n: thread t = m (coalesced 2B reads across t). [R8]
__global__ __launch_bounds__(256) void k_colbuf(
    const unsigned short* __restrict__ part, const float* __restrict__ b3,
    const float* __restrict__ w4, const float* __restrict__ b4,
    float* __restrict__ colbuf)
{
  __shared__ float red[2][4];
  const int n = blockIdx.x;
  const int t = threadIdx.x;
  const unsigned short* p = part + (size_t)n * MSTRIDE + t;
  float s = 0.f;
#pragma unroll
  for (int kcc = 0; kcc < KSPLIT; ++kcc)
    s += bf2f(p[(size_t)kcc * PART_KC]);
  float e = 0.f, c4 = 0.f;
  if (t < C2) {
    e  = fmaxf(s + b3[t], 0.f);
    c4 = w4[t] * e;
  }
#pragma unroll
  for (int off = 32; off; off >>= 1) {
    e  += __shfl_xor(e, off);
    c4 += __shfl_xor(c4, off);
  }
  const int wv = t >> 6;
  if ((t & 63) == 0) { red[0][wv] = e; red[1][wv] = c4; }
  __syncthreads();
  if (t == 0) {
    const float cs  = red[0][0] + red[0][1] + red[0][2] + red[0][3];
    const float tc4 = red[1][0] + red[1][1] + red[1][2] + red[1][3] + b4[0];
    const float mask = 1.f / (1.f + expf(-tc4));
    colbuf[n] = cs * (1.f + mask) * (1.f / (float)L_DIM);
  }
}

// ---------------- Stage 3: broadcast to all nodes (R8 form, proven) --------
__global__ __launch_bounds__(256) void k_broadcast(
    const float* __restrict__ colbuf, float4* __restrict__ out)
{
  const size_t idx = (size_t)blockIdx.x * 256 + threadIdx.x;  // float4 index
  const int nq = (int)(idx & 255);
  const float4 v = *(const float4*)(colbuf + nq * 4);
  out[idx] = v;
}

extern "C" void kernel_launch(void* const* d_in, const int* in_sizes, int n_in,
                              void* d_out, int out_size, void* d_ws, size_t ws_size,
                              hipStream_t stream) {
  // inputs: x, edge_index, edge_attr, conv3_w, conv3_b, conv4_w, conv4_b
  const float* edge_attr = (const float*)d_in[2];   // [8192][1024]
  const float* w3        = (const float*)d_in[3];   // [240][8192]
  const float* b3        = (const float*)d_in[4];   // [240]
  const float* w4        = (const float*)d_in[5];   // [240]
  const float* b4        = (const float*)d_in[6];   // [1]

  float* out = (float*)d_out;

  // partials in d_ws (measured ws_size ~268MB >> 8.4MB); colbuf after them.
  unsigned short* part;
  float* colbuf;
  if (ws_size >= PART_BYTES + 4096) {
    part   = (unsigned short*)d_ws;
    colbuf = (float*)((char*)d_ws + PART_BYTES);
  } else {
    part   = (unsigned short*)d_out;   // overwritten by broadcast afterwards
    colbuf = (float*)d_ws;
  }

  k_gemm      <<<dim3(512),   512, 0, stream>>>(w3, edge_attr, part);
  k_colbuf    <<<dim3(1024),  256, 0, stream>>>(part, b3, w4, b4, colbuf);
  k_broadcast <<<dim3(10000), 256, 0, stream>>>(colbuf, (float4*)out);
}

// Round 13
// 31.315 us; speedup vs baseline: 5.6138x; 1.0211x over previous
//
#include <hip/hip_runtime.h>
#include <hip/hip_bf16.h>

#define K_DIM 8192
#define L_DIM 1024
#define C2 240
#define MSTRIDE 256                 // padded m stride in partials
#define BM 128
#define BN 128
#define BK 64
#define KSPLIT 16
#define KCHUNK 512                  // K_DIM / KSPLIT
#define NSTEP 8                     // KCHUNK / BK
#define PART_KC (L_DIM * MSTRIDE)   // 262144 bf16 elems per k-chunk
#define PART_BYTES ((size_t)KSPLIT * PART_KC * 2)  // 8,388,608
#define TOT_F4 (10000 * 256)

typedef __attribute__((ext_vector_type(4))) float f32x4;
typedef __attribute__((ext_vector_type(2))) float f32x2;
typedef __attribute__((ext_vector_type(8))) short bf16x8;
typedef __attribute__((ext_vector_type(4))) short bf16x4;

__device__ __forceinline__ unsigned short f2bf(float f) {
  return __builtin_bit_cast(unsigned short, __float2bfloat16(f));
}
__device__ __forceinline__ float bf2f(unsigned short h) {
  unsigned u = ((unsigned)h) << 16;
  return __builtin_bit_cast(float, u);
}

// lgkm-only barrier: ds_writes visible, but in-flight GLOBAL loads stay
// pending (HIP __syncthreads would emit s_waitcnt vmcnt(0) and drain the
// depth-2 prefetch every step — the m97 barrier-drain stall).
// Safety: each wave's ds_reads complete (compiler lgkm wait before MFMA)
// before it reaches the NEXT barrier, so buf X written at step s is read
// at s and next written at s+2 — two barriers apart, no race.
__device__ __forceinline__ void barrier_lgkm_only() {
  __builtin_amdgcn_sched_barrier(0);
  asm volatile("s_waitcnt lgkmcnt(0)" ::: "memory");
  __builtin_amdgcn_s_barrier();
  __builtin_amdgcn_sched_barrier(0);
}

// ---------------- Stage 1: bf16 MFMA K-split GEMM (R8 body) ----------------
// part[kc][n][m(pad 256)] = (W[240][8192] @ A[8192][1024]) k-chunk partials.
// 256 blocks x 512 thr (8 waves: 2m x 4n of 64x32). KSPLIT=16, NSTEP=8,
// depth-2 register prefetch + double-buffered LDS, ONE lgkm-only barrier
// per step (the only change vs R8's 31.3us config).
__global__ __launch_bounds__(512, 2) void k_gemm(
    const float* __restrict__ Wm, const float* __restrict__ Am,
    unsigned short* __restrict__ part)
{
  __shared__ __align__(16) unsigned short sW[2 * BM * BK];  // 32 KB dbuf
  __shared__ __align__(16) unsigned short sA[2 * BN * BK];  // 32 KB dbuf

  const int t    = threadIdx.x;
  const int lane = t & 63;
  const int bid  = blockIdx.x;

  // XCD-chunked remap (bijective, 256 % 8 == 0): XCD owns 2 kc x all tiles.
  const int wk    = (bid & 7) * 32 + (bid >> 3);
  const int nt8   = wk & 7;
  const int mtile = (wk >> 3) & 1;
  const int kc    = wk >> 4;            // 0..15

  const int wid = t >> 6;
  const int mg  = wid >> 2;       // 2 groups of 64 m
  const int ng  = wid & 3;        // 4 groups of 32 n
  const int l15 = lane & 15;
  const int lk8 = (lane >> 4) * 8;

  const int n0b = nt8 * BN;
  const int m0b = mtile * BM;
  const int k0  = kc * KCHUNK;

  // W staging: thread -> (row t>>2, 16 k at (t&3)*16); 4 f32x4 loads.
  const int swm = t >> 2;
  const int swk = (t & 3) * 16;
  // A staging: thread -> (2 cols at 2*(t&63), 8 k at wid*8); 8 f32x2 loads.
  const int san = (t & 63) * 2;
  const int sak = (t >> 6) * 8;

  const float* wp = Wm + (size_t)(m0b + swm) * K_DIM + k0 + swk;
  const float* ap = Am + (size_t)(k0 + sak) * L_DIM + n0b + san;
  const bool wok = (m0b + swm) < C2;

  f32x4 wregs[2][4];
  f32x2 aregs[2][8];
  f32x4 acc[4][2];
#pragma unroll
  for (int i = 0; i < 4; ++i)
#pragma unroll
    for (int j = 0; j < 2; ++j) acc[i][j] = (f32x4){0.f, 0.f, 0.f, 0.f};

  // prologue: issue loads for steps 0 and 1 (depth-2)
#pragma unroll
  for (int p = 0; p < 2; ++p) {
#pragma unroll
    for (int j = 0; j < 4; ++j)
      wregs[p][j] = wok ? *(const f32x4*)(wp + p * BK + 4 * j)
                        : (f32x4){0.f, 0.f, 0.f, 0.f};
#pragma unroll
    for (int r = 0; r < 8; ++r)
      aregs[p][r] = *(const f32x2*)(ap + (size_t)(p * BK + r) * L_DIM);
  }

#pragma unroll
  for (int s = 0; s < NSTEP; ++s) {
    unsigned short* swb = sW + (s & 1) * (BM * BK);
    unsigned short* sab = sA + (s & 1) * (BN * BK);

    // ---- convert + swizzled LDS write from reg set s&1 ----
    // (compiler inserts a COUNTED vmcnt here for just these regs' loads;
    //  the s+1 prefetch stays in flight)
#pragma unroll
    for (int j = 0; j < 2; ++j) {       // two bf16x8 per thread (16 k)
      f32x4 a = wregs[s & 1][2 * j], b = wregs[s & 1][2 * j + 1];
      bf16x8 v;
      v[0] = (short)f2bf(a[0]); v[1] = (short)f2bf(a[1]);
      v[2] = (short)f2bf(a[2]); v[3] = (short)f2bf(a[3]);
      v[4] = (short)f2bf(b[0]); v[5] = (short)f2bf(b[1]);
      v[6] = (short)f2bf(b[2]); v[7] = (short)f2bf(b[3]);
      *(bf16x8*)&swb[swm * BK + ((swk + 8 * j) ^ ((swm & 7) << 3))] = v;
    }
#pragma unroll
    for (int j = 0; j < 2; ++j) {       // two cols, 8 k each
      const int n = san + j;
      bf16x8 v;
#pragma unroll
      for (int r = 0; r < 8; ++r)
        v[r] = (short)f2bf(j ? aregs[s & 1][r][1] : aregs[s & 1][r][0]);
      *(bf16x8*)&sab[n * BK + (sak ^ ((n & 7) << 3))] = v;
    }

    barrier_lgkm_only();   // NOT __syncthreads(): no vmcnt(0) drain

    // ---- issue loads for step s+2 into reg set s&1 (depth-2 cover) ----
    if (s + 2 < NSTEP) {
      const float* wp2 = wp + (s + 2) * BK;
      const float* ap2 = ap + (size_t)(s + 2) * BK * L_DIM;
#pragma unroll
      for (int j = 0; j < 4; ++j)
        wregs[s & 1][j] = wok ? *(const f32x4*)(wp2 + 4 * j)
                              : (f32x4){0.f, 0.f, 0.f, 0.f};
#pragma unroll
      for (int r = 0; r < 8; ++r)
        aregs[s & 1][r] = *(const f32x2*)(ap2 + (size_t)r * L_DIM);
    }

    // ---- compute from LDS buffer s&1 ----
#pragma unroll
    for (int kk = 0; kk < BK; kk += 32) {
      bf16x8 wf[4], af[2];
#pragma unroll
      for (int mt = 0; mt < 4; ++mt) {
        int m = mg * 64 + mt * 16 + l15;
        wf[mt] = *(const bf16x8*)&swb[m * BK + ((kk + lk8) ^ ((m & 7) << 3))];
      }
#pragma unroll
      for (int nt = 0; nt < 2; ++nt) {
        int n = ng * 32 + nt * 16 + l15;
        af[nt] = *(const bf16x8*)&sab[n * BK + ((kk + lk8) ^ ((n & 7) << 3))];
      }
#pragma unroll
      for (int mt = 0; mt < 4; ++mt)
#pragma unroll
        for (int nt = 0; nt < 2; ++nt)
          acc[mt][nt] = __builtin_amdgcn_mfma_f32_16x16x32_bf16(
              wf[mt], af[nt], acc[mt][nt], 0, 0, 0);
    }
    // single barrier/step: next iteration writes the other LDS buffer
  }

  // ---- store transposed bf16 partials: part[kc][n][m] ----
  unsigned short* pb = part + (size_t)kc * PART_KC;
#pragma unroll
  for (int mt = 0; mt < 4; ++mt) {
    const int m0 = m0b + mg * 64 + mt * 16 + (lane >> 4) * 4;
#pragma unroll
    for (int nt = 0; nt < 2; ++nt) {
      const int n = n0b + ng * 32 + nt * 16 + l15;
      bf16x4 v;
      v[0] = (short)f2bf(acc[mt][nt][0]);
      v[1] = (short)f2bf(acc[mt][nt][1]);
      v[2] = (short)f2bf(acc[mt][nt][2]);
      v[3] = (short)f2bf(acc[mt][nt][3]);
      *(bf16x4*)&pb[(size_t)n * MSTRIDE + m0] = v;
    }
  }
}

// ---------------- Stage 2: kc-reduce + bias + ReLU + m-reductions ----------
// One block per column n: thread t = m (coalesced 2B reads across t). [R8]
__global__ __launch_bounds__(256) void k_colbuf(
    const unsigned short* __restrict__ part, const float* __restrict__ b3,
    const float* __restrict__ w4, const float* __restrict__ b4,
    float* __restrict__ colbuf)
{
  __shared__ float red[2][4];
  const int n = blockIdx.x;
  const int t = threadIdx.x;
  const unsigned short* p = part + (size_t)n * MSTRIDE + t;
  float s = 0.f;
#pragma unroll
  for (int kcc = 0; kcc < KSPLIT; ++kcc)
    s += bf2f(p[(size_t)kcc * PART_KC]);
  float e = 0.f, c4 = 0.f;
  if (t < C2) {
    e  = fmaxf(s + b3[t], 0.f);
    c4 = w4[t] * e;
  }
#pragma unroll
  for (int off = 32; off; off >>= 1) {
    e  += __shfl_xor(e, off);
    c4 += __shfl_xor(c4, off);
  }
  const int wv = t >> 6;
  if ((t & 63) == 0) { red[0][wv] = e; red[1][wv] = c4; }
  __syncthreads();
  if (t == 0) {
    const float cs  = red[0][0] + red[0][1] + red[0][2] + red[0][3];
    const float tc4 = red[1][0] + red[1][1] + red[1][2] + red[1][3] + b4[0];
    const float mask = 1.f / (1.f + expf(-tc4));
    colbuf[n] = cs * (1.f + mask) * (1.f / (float)L_DIM);
  }
}

// ---------------- Stage 3: broadcast to all nodes (R8 form, proven) --------
__global__ __launch_bounds__(256) void k_broadcast(
    const float* __restrict__ colbuf, float4* __restrict__ out)
{
  const size_t idx = (size_t)blockIdx.x * 256 + threadIdx.x;  // float4 index
  const int nq = (int)(idx & 255);
  const float4 v = *(const float4*)(colbuf + nq * 4);
  out[idx] = v;
}

extern "C" void kernel_launch(void* const* d_in, const int* in_sizes, int n_in,
                              void* d_out, int out_size, void* d_ws, size_t ws_size,
                              hipStream_t stream) {
  // inputs: x, edge_index, edge_attr, conv3_w, conv3_b, conv4_w, conv4_b
  const float* edge_attr = (const float*)d_in[2];   // [8192][1024]
  const float* w3        = (const float*)d_in[3];   // [240][8192]
  const float* b3        = (const float*)d_in[4];   // [240]
  const float* w4        = (const float*)d_in[5];   // [240]
  const float* b4        = (const float*)d_in[6];   // [1]

  float* out = (float*)d_out;

  // partials in d_ws (measured ws_size ~268MB >> 8.4MB); colbuf after them.
  unsigned short* part;
  float* colbuf;
  if (ws_size >= PART_BYTES + 4096) {
    part   = (unsigned short*)d_ws;
    colbuf = (float*)((char*)d_ws + PART_BYTES);
  } else {
    part   = (unsigned short*)d_out;   // overwritten by broadcast afterwards
    colbuf = (float*)d_ws;
  }

  k_gemm      <<<dim3(256),   512, 0, stream>>>(w3, edge_attr, part);
  k_colbuf    <<<dim3(1024),  256, 0, stream>>>(part, b3, w4, b4, colbuf);
  k_broadcast <<<dim3(10000), 256, 0, stream>>>(colbuf, (float4*)out);
}